// Round 1
// baseline (168.286 us; speedup 1.0000x reference)
//
#include <hip/hip_runtime.h>
#include <cstdint>
#include <cstddef>

typedef __attribute__((ext_vector_type(8))) short short8;
typedef __attribute__((ext_vector_type(4))) float f32x4;

#define MFMA16(a,b,c) __builtin_amdgcn_mfma_f32_16x16x32_bf16((a),(b),(c),0,0,0)

__device__ __forceinline__ unsigned short f2bf(float f) {
  union { float f; unsigned u; } v; v.f = f;
  unsigned r = v.u + 0x7fffu + ((v.u >> 16) & 1u);
  return (unsigned short)(r >> 16);
}
__device__ __forceinline__ float bf2f(unsigned short h) {
  union { unsigned u; float f; } v; v.u = ((unsigned)h) << 16;
  return v.f;
}

// ---------------- K0: feat [b][c][p] f32 -> featT [b][p][c] bf16 ----------------
__global__ __launch_bounds__(256) void k_transpose(const float* __restrict__ feat,
                                                   unsigned short* __restrict__ featT) {
  __shared__ unsigned short sm[64][66];
  const int t = threadIdx.x;
  const int b = blockIdx.z, c0 = blockIdx.y * 64, p0 = blockIdx.x * 64;
  const int pp = t & 63, ccb = t >> 6;
  const float* src = feat + ((size_t)(b * 256 + c0)) * 4096 + p0;
  for (int it = 0; it < 16; ++it) {
    int cc = ccb + it * 4;
    sm[cc][pp] = f2bf(src[(size_t)cc * 4096 + pp]);
  }
  __syncthreads();
  const int po = t >> 2, g0 = t & 3;
  for (int it = 0; it < 2; ++it) {
    int grp = g0 + it * 4;
    unsigned short us[8];
#pragma unroll
    for (int j = 0; j < 8; ++j) us[j] = sm[grp * 8 + j][po];
    uint4 pk;
    pk.x = us[0] | ((unsigned)us[1] << 16);
    pk.y = us[2] | ((unsigned)us[3] << 16);
    pk.z = us[4] | ((unsigned)us[5] << 16);
    pk.w = us[6] | ((unsigned)us[7] << 16);
    *(uint4*)&featT[((size_t)(b * 4096 + p0 + po)) * 256 + c0 + grp * 8] = pk;
  }
}

// ---------------- K0b: weight f32 -> bf16 ----------------
__global__ __launch_bounds__(256) void k_wcvt(const float* __restrict__ w_val,
                                              const float* __restrict__ w_red,
                                              unsigned short* __restrict__ wv,
                                              unsigned short* __restrict__ wr) {
  int i = blockIdx.x * 256 + threadIdx.x;
  if (i < 65536) wv[i] = f2bf(w_val[i]);
  int j = i - 65536;
  if (j >= 0 && j < 8192) wr[j] = f2bf(w_red[j]);
}

// ---------------- K1: A = relu(featT @ w_red^T + b_red), sq = rowsum(A^2) ----------------
// A stored bf16 [b][p(4096)][ci(32)]; sq f32 [b][p]. sq computed from the ROUNDED A.
__global__ __launch_bounds__(256) void k_red(const unsigned short* __restrict__ featT,
                                             const unsigned short* __restrict__ wr,
                                             const float* __restrict__ b_red,
                                             unsigned short* __restrict__ A,
                                             float* __restrict__ sq) {
  const int t = threadIdx.x, w = t >> 6, lane = t & 63, a = lane & 15, g = lane >> 4;
  const int b = blockIdx.y, p0 = blockIdx.x * 64;
  const int p_row = p0 + w * 16 + a;
  f32x4 acc[2] = {{0,0,0,0},{0,0,0,0}};
  const unsigned short* fp = featT + ((size_t)(b * 4096 + p_row)) * 256;
#pragma unroll
  for (int kk = 0; kk < 8; ++kk) {
    short8 af = *(const short8*)&fp[kk * 32 + g * 8];
#pragma unroll
    for (int s = 0; s < 2; ++s) {
      short8 bf = *(const short8*)&wr[(s * 16 + a) * 256 + kk * 32 + g * 8];
      acc[s] = MFMA16(af, bf, acc[s]);
    }
  }
  float b0 = b_red[a], b1 = b_red[16 + a];
  float rowsum[4] = {0, 0, 0, 0};
  unsigned short outs[2][4];
#pragma unroll
  for (int s = 0; s < 2; ++s) {
    float bias = s ? b1 : b0;
#pragma unroll
    for (int r = 0; r < 4; ++r) {
      float v = acc[s][r] + bias;
      v = v > 0.f ? v : 0.f;
      unsigned short h = f2bf(v);
      outs[s][r] = h;
      float vb = bf2f(h);
      rowsum[r] += vb * vb;
    }
  }
  unsigned short* Ab = A + ((size_t)b * 4096 + p0 + w * 16) * 32;
#pragma unroll
  for (int s = 0; s < 2; ++s)
#pragma unroll
    for (int r = 0; r < 4; ++r)
      Ab[(g * 4 + r) * 32 + s * 16 + a] = outs[s][r];
#pragma unroll
  for (int off = 1; off < 16; off <<= 1) {
#pragma unroll
    for (int r = 0; r < 4; ++r) rowsum[r] += __shfl_xor(rowsum[r], off, 64);
  }
  if (a == 0) {
    f32x4 sv = {rowsum[0], rowsum[1], rowsum[2], rowsum[3]};
    *(f32x4*)&sq[(size_t)b * 4096 + p0 + w * 16 + g * 4] = sv;
  }
}

// ---------------- K3: val = relu(w_val @ feat + b_val), bf16 [b][o(256)][p(4096)] ----------------
__global__ __launch_bounds__(512) void k_val(const unsigned short* __restrict__ featT,
                                             const unsigned short* __restrict__ wv,
                                             const float* __restrict__ b_val,
                                             unsigned short* __restrict__ val) {
  const int t = threadIdx.x, w = t >> 6, lane = t & 63, a = lane & 15, g = lane >> 4;
  const int b = blockIdx.y, p0 = blockIdx.x * 64;
  f32x4 acc[2][4] = {};
#pragma unroll 2
  for (int kk = 0; kk < 8; ++kk) {
    short8 bfr[4];
#pragma unroll
    for (int ms = 0; ms < 4; ++ms)
      bfr[ms] = *(const short8*)&featT[((size_t)(b * 4096 + p0 + ms * 16 + a)) * 256 + kk * 32 + g * 8];
#pragma unroll
    for (int s = 0; s < 2; ++s) {
      short8 af = *(const short8*)&wv[(w * 32 + s * 16 + a) * 256 + kk * 32 + g * 8];
#pragma unroll
      for (int ms = 0; ms < 4; ++ms)
        acc[s][ms] = MFMA16(af, bfr[ms], acc[s][ms]);
    }
  }
#pragma unroll
  for (int s = 0; s < 2; ++s) {
    f32x4 bv = *(const f32x4*)&b_val[w * 32 + s * 16 + g * 4];
#pragma unroll
    for (int ms = 0; ms < 4; ++ms) {
#pragma unroll
      for (int r = 0; r < 4; ++r) {
        float v = acc[s][ms][r] + bv[r];
        v = v > 0.f ? v : 0.f;
        int o = w * 32 + s * 16 + g * 4 + r;
        val[((size_t)(b * 256 + o)) * 4096 + p0 + ms * 16 + a] = f2bf(v);
      }
    }
  }
}

// ---------------- K4: fused mask + (val @ mask) + residual ----------------
// grid (64 m-tiles, 4 b), 512 thr (8 waves). Wave w: S-subtiles (nsub=w&3, msub=2*(w>>2)+h),
// GEMM2 rows c in [32w, 32w+32).
__global__ __launch_bounds__(512) void k_fused(const unsigned short* __restrict__ A,
                                               const float* __restrict__ sq,
                                               const unsigned short* __restrict__ val,
                                               const float* __restrict__ feat,
                                               float* __restrict__ dout) {
  __shared__ unsigned short ldsT[2][64][72];  // [buf][m][n], stride 72 bf16 = 144B (16B aligned, conflict-free)
  const int t = threadIdx.x, w = t >> 6, lane = t & 63, a = lane & 15, g = lane >> 4;
  const int nsub = w & 3, mh = w >> 2;
  const int b = blockIdx.y, m0 = blockIdx.x * 64;
  const unsigned short* Ab = A + (size_t)b * 4096 * 32;
  const float* sqb = sq + (size_t)b * 4096;

  short8 am[2];
  float sqm[2];
#pragma unroll
  for (int h = 0; h < 2; ++h) {
    int m = m0 + (2 * mh + h) * 16 + a;
    am[h] = *(const short8*)&Ab[(size_t)m * 32 + g * 8];
    sqm[h] = sqb[m];
  }
  f32x4 acc[2][4] = {};
  float* maskout = dout + 4194304 + (size_t)b * 16777216;

  for (int tt = 0; tt < 64; ++tt) {
    const int n0 = tt * 64;
    const int buf = tt & 1;
    // loads for this step (L1/L2 resident)
    short8 an = *(const short8*)&Ab[(size_t)(n0 + nsub * 16 + a) * 32 + g * 8];
    f32x4 sqn = *(const f32x4*)&sqb[n0 + nsub * 16 + g * 4];
    short8 vf[2][2];
#pragma unroll
    for (int cs = 0; cs < 2; ++cs)
#pragma unroll
      for (int ks = 0; ks < 2; ++ks)
        vf[cs][ks] = *(const short8*)&val[((size_t)(b * 256 + w * 32 + cs * 16 + a)) * 4096 + n0 + ks * 32 + g * 8];
    // S = A_n . A_m^T  (K=32, one MFMA per subtile)
    f32x4 zero = {0, 0, 0, 0};
    f32x4 sfr[2];
#pragma unroll
    for (int h = 0; h < 2; ++h) sfr[h] = MFMA16(an, am[h], zero);
    // mask = sigmoid(exp(-D)), D = sqn + sqm - 2S  (exact sq-dist of rounded A)
    float mk[2][4];
#pragma unroll
    for (int h = 0; h < 2; ++h) {
#pragma unroll
      for (int r = 0; r < 4; ++r) {
        float t2 = sqn[r] + sqm[h];
        float u = __expf(fmaf(2.f, sfr[h][r], -t2));  // exp(-D)
        // sigmoid(u) on [0,1]: 0.5 + u/4 - u^3/48 + u^5/480  (|err| <= 2.2e-4)
        float u2 = u * u;
        float pa = fmaf(u2, 2.0833333e-3f, -2.0833333e-2f);
        float pb = fmaf(u2, pa, 0.25f);
        mk[h][r] = fmaf(u, pb, 0.5f);
      }
    }
    // transpose-store mask tile into LDS as bf16 [m][n]
#pragma unroll
    for (int h = 0; h < 2; ++h) {
      uint2 pk;
      pk.x = f2bf(mk[h][0]) | ((unsigned)f2bf(mk[h][1]) << 16);
      pk.y = f2bf(mk[h][2]) | ((unsigned)f2bf(mk[h][3]) << 16);
      *(uint2*)&ldsT[buf][(2 * mh + h) * 16 + a][nsub * 16 + g * 4] = pk;
    }
    __syncthreads();
    // f32 mask stores issued after the barrier: they drain under GEMM2
#pragma unroll
    for (int h = 0; h < 2; ++h) {
#pragma unroll
      for (int r = 0; r < 4; ++r) {
        int n = n0 + nsub * 16 + g * 4 + r;
        maskout[(size_t)n * 4096 + m0 + (2 * mh + h) * 16 + a] = mk[h][r];
      }
    }
    // GEMM2: acc[c, m] += val[c, n-tile] @ mask[n-tile, m]
#pragma unroll
    for (int ks = 0; ks < 2; ++ks) {
      short8 bfr[4];
#pragma unroll
      for (int ms = 0; ms < 4; ++ms)
        bfr[ms] = *(const short8*)&ldsT[buf][ms * 16 + a][ks * 32 + g * 8];
#pragma unroll
      for (int cs = 0; cs < 2; ++cs)
#pragma unroll
        for (int ms = 0; ms < 4; ++ms)
          acc[cs][ms] = MFMA16(vf[cs][ks], bfr[ms], acc[cs][ms]);
    }
  }
  // epilogue: out = acc + features
  const float* fb = feat + (size_t)b * 256 * 4096;
  float* ob = dout + (size_t)b * 256 * 4096;
#pragma unroll
  for (int cs = 0; cs < 2; ++cs) {
#pragma unroll
    for (int ms = 0; ms < 4; ++ms) {
#pragma unroll
      for (int r = 0; r < 4; ++r) {
        int c = w * 32 + cs * 16 + g * 4 + r;
        int m = m0 + ms * 16 + a;
        size_t idx = (size_t)c * 4096 + m;
        ob[idx] = acc[cs][ms][r] + fb[idx];
      }
    }
  }
}

extern "C" void kernel_launch(void* const* d_in, const int* in_sizes, int n_in,
                              void* d_out, int out_size, void* d_ws, size_t ws_size,
                              hipStream_t stream) {
  const float* feat  = (const float*)d_in[0];
  const float* w_red = (const float*)d_in[1];
  const float* b_red = (const float*)d_in[2];
  const float* w_val = (const float*)d_in[3];
  const float* b_val = (const float*)d_in[4];
  float* out = (float*)d_out;
  char* ws = (char*)d_ws;
  // workspace layout (17.2 MB total)
  unsigned short* featT = (unsigned short*)ws;              // 8,388,608 B
  unsigned short* A     = (unsigned short*)(ws + 8388608);  // 1,048,576 B
  float*          sq    = (float*)        (ws + 9437184);   //    65,536 B
  unsigned short* wv    = (unsigned short*)(ws + 9502720);  //   131,072 B
  unsigned short* wr    = (unsigned short*)(ws + 9633792);  //    16,384 B
  unsigned short* val   = (unsigned short*)(ws + 9650176);  // 8,388,608 B

  k_transpose<<<dim3(64, 4, 4), 256, 0, stream>>>(feat, featT);
  k_wcvt<<<dim3(288), 256, 0, stream>>>(w_val, w_red, wv, wr);
  k_red<<<dim3(64, 4), 256, 0, stream>>>(featT, wr, b_red, A, sq);
  k_val<<<dim3(64, 4), 512, 0, stream>>>(featT, wv, b_val, val);
  k_fused<<<dim3(64, 4), 512, 0, stream>>>(A, sq, val, feat, out);
}